// Round 1
// 232.494 us; speedup vs baseline: 1.0297x; 1.0297x over previous
//
#include <hip/hip_runtime.h>
#include <hip/hip_bf16.h>
#include <cstdint>
#include <cstddef>

#define D 128           // feature dim
#define KNB 10          // NUM_NEIGHBORS
#define SENT 0x7FFFFFFF
#define SHIFT 8         // nodes per bucket = 256
#define NPB 256
#define T_BIN 256
#define EPB 4096        // edges per binning block
#define MAXNB 1024

typedef __attribute__((ext_vector_type(8))) short short8;   // MFMA A/B frag (8 bf16)
typedef __attribute__((ext_vector_type(4))) float floatx4;  // MFMA C/D frag

__device__ inline unsigned bf16_rne(float f) {
  unsigned u = __builtin_bit_cast(unsigned, f);
  return (u + 0x7FFFu + ((u >> 16) & 1u)) >> 16;
}
__device__ inline float bflo(unsigned u) { return __builtin_bit_cast(float, u << 16); }
__device__ inline float bfhi(unsigned u) { return __builtin_bit_cast(float, u & 0xFFFF0000u); }

// ---------------------------------------------------------------------------
// k_init: counts[0..NB)=0 only. R7: slots init DROPPED — k_select provably
// writes every entry of slots[0, N*KNB) (union of [nbase*KNB, nbase*KNB +
// nloc*KNB) over all buckets == [0, N*KNB)), so the SENT pre-fill was dead.
// ---------------------------------------------------------------------------
__global__ __launch_bounds__(256) void k_init(int* __restrict__ counts, int NB) {
  int i = blockIdx.x * 256 + threadIdx.x;
  if (i < NB) counts[i] = 0;
}

// ---------------------------------------------------------------------------
// k_count_xcast: blocks [0,blocks_bin) do the LDS-histogram edge count;
// blocks [blocks_bin,..) stream-cast x fp32 -> xh bf16 pairs (overlapped).
// ---------------------------------------------------------------------------
__global__ __launch_bounds__(T_BIN) void k_count_xcast(const int* __restrict__ row, int E,
                                                       int NB, int* __restrict__ counts,
                                                       int blocks_bin,
                                                       const float* __restrict__ x,
                                                       unsigned* __restrict__ xh, int n8) {
  if ((int)blockIdx.x < blocks_bin) {
    __shared__ int hist[MAXNB];
    for (int i = threadIdx.x; i < NB; i += T_BIN) hist[i] = 0;
    __syncthreads();
    int e0 = blockIdx.x * EPB;
    for (int i = threadIdx.x; i < EPB; i += T_BIN) {
      int e = e0 + i;
      if (e < E) atomicAdd(&hist[row[e] >> SHIFT], 1);
    }
    __syncthreads();
    for (int i = threadIdx.x; i < NB; i += T_BIN)
      if (hist[i]) atomicAdd(&counts[i], hist[i]);
  } else {
    int t = ((int)blockIdx.x - blocks_bin) * T_BIN + threadIdx.x;
    if (t >= n8) return;
    const float4* p = reinterpret_cast<const float4*>(x) + (size_t)t * 2;
    float4 a = p[0], b = p[1];
    uint4 o;
    o.x = bf16_rne(a.x) | (bf16_rne(a.y) << 16);
    o.y = bf16_rne(a.z) | (bf16_rne(a.w) << 16);
    o.z = bf16_rne(b.x) | (bf16_rne(b.y) << 16);
    o.w = bf16_rne(b.z) | (bf16_rne(b.w) << 16);
    reinterpret_cast<uint4*>(xh)[t] = o;
  }
}

// ---------------------------------------------------------------------------
__global__ __launch_bounds__(MAXNB) void k_scan(const int* __restrict__ counts, int NB,
                                                int* __restrict__ bases,
                                                int* __restrict__ cursor) {
  __shared__ int buf[MAXNB];
  int t = threadIdx.x;
  int v = (t < NB) ? counts[t] : 0;
  buf[t] = v;
  __syncthreads();
  for (int off = 1; off < MAXNB; off <<= 1) {
    int xv = (t >= off) ? buf[t - off] : 0;
    __syncthreads();
    buf[t] += xv;
    __syncthreads();
  }
  if (t < NB) {
    int base = buf[t] - v;
    bases[t] = base;
    cursor[t] = base;
  }
}

// ---------------------------------------------------------------------------
// bin edges into bucket regions; entry = (row&255)<<24 | edge_id (E < 2^24)
// ---------------------------------------------------------------------------
__global__ __launch_bounds__(T_BIN) void k_scatter2(const int* __restrict__ row, int E,
                                                    int NB, int* __restrict__ cursor,
                                                    unsigned* __restrict__ binned) {
  __shared__ int hist[MAXNB];
  __shared__ int lbase[MAXNB];
  for (int i = threadIdx.x; i < NB; i += T_BIN) hist[i] = 0;
  __syncthreads();
  int e0 = blockIdx.x * EPB;
  for (int i = threadIdx.x; i < EPB; i += T_BIN) {
    int e = e0 + i;
    if (e < E) atomicAdd(&hist[row[e] >> SHIFT], 1);
  }
  __syncthreads();
  for (int i = threadIdx.x; i < NB; i += T_BIN) {
    int h = hist[i];
    lbase[i] = h ? atomicAdd(&cursor[i], h) : 0;
  }
  __syncthreads();
  for (int i = threadIdx.x; i < NB; i += T_BIN) hist[i] = 0;  // reuse as cursor
  __syncthreads();
  for (int i = threadIdx.x; i < EPB; i += T_BIN) {
    int e = e0 + i;
    if (e < E) {
      int r = row[e];
      int b = r >> SHIFT;
      int pos = lbase[b] + atomicAdd(&hist[b], 1);
      binned[pos] = ((unsigned)(r & (NPB - 1)) << 24) | (unsigned)e;
    }
  }
}

// ---------------------------------------------------------------------------
// one WG per bucket: LDS atomicMin cascade -> 10 smallest edge ids per node.
// R7: the dump now maps edge-id -> COLUMN (ei[E+eid]) before writing slots.
// The mean only needs the SET of first-10 edges, not their order, so storing
// cols is equivalent — and it removes one serial random load (the ei hop)
// from every k_agg wave's latency chain. The ~1M random 4B col gathers here
// overlap the LDS cascade + dump. HARDENING: (unsigned)v < E rejects SENT
// and any poison-derived value BEFORE indexing ei; invalid -> -1.
// ---------------------------------------------------------------------------
__global__ __launch_bounds__(256) void k_select(const unsigned* __restrict__ binned,
                                                const int* __restrict__ bases,
                                                const int* __restrict__ counts,
                                                const int* __restrict__ ei,
                                                int* __restrict__ slots_g, int N, int E) {
  __shared__ int sl[NPB * KNB];
  int b = blockIdx.x;
  int nbase = b << SHIFT;
  int nloc = min(NPB, N - nbase);
  for (int i = threadIdx.x; i < nloc * KNB; i += 256) sl[i] = SENT;
  __syncthreads();
  int base = bases[b];
  int cnt = counts[b];
  if (cnt > E) cnt = E;  // hardening
  for (int i = threadIdx.x; i < cnt; i += 256) {
    unsigned en = binned[base + i];
    int rl = (int)(en >> 24);
    int v = (int)(en & 0xFFFFFFu);
    int* s = &sl[rl * KNB];
#pragma unroll
    for (int k = 0; k < KNB; ++k) {
      int old = atomicMin(&s[k], v);
      if (old == SENT) break;
      v = v > old ? v : old;
    }
  }
  __syncthreads();
  for (int i = threadIdx.x; i < nloc * KNB; i += 256) {
    int v = sl[i];
    int col = ((unsigned)v < (unsigned)E) ? ei[(size_t)E + v] : -1;
    slots_g[(size_t)nbase * KNB + i] = col;
  }
}

// ---------------------------------------------------------------------------
// k_agg_hb: neighbor mean via bf16 gather, fp32 accumulate, bf16 packed out.
// R7 restructure: 4 nodes per WAVE (16-lane groups), uint4 (16B/lane) gathers.
//  - slots now hold COLUMNS (k_select maps eid->col), so the chain is just
//    {slot load -> shfl -> 10 gathers}; the serial ei hop is gone.
//  - 40 independent 16B loads in flight per wave (vs 10x4B before): 4x MLP,
//    4x fewer waves, identical bytes. Targets the latency-limited 3.65 TB/s.
// HARDENING (load-bearing, see R3/R5 post-mortems): col range-checked
// ((unsigned)c < N) before indexing xh; invalid/SENT/poison -> weight 0,
// gather row 0 (hot line).
// ---------------------------------------------------------------------------
__global__ __launch_bounds__(256) void k_agg_hb(const unsigned* __restrict__ xh,
                                                const float* __restrict__ x,
                                                const int* __restrict__ slots,
                                                unsigned* __restrict__ aggbh,
                                                int N) {
  const int lane = threadIdx.x & 63;
  const int j16 = lane & 15;       // dim-octet index within the 256B row
  const int gsh = lane & 48;       // group base lane within wave (gw*16)
  const int n = blockIdx.x * 16 + (threadIdx.x >> 4);
  const bool active = n < N;

  int scol = -1;
  if (active && j16 < KNB) scol = slots[(size_t)n * KNB + j16];
  bool valid = (unsigned)scol < (unsigned)N;
  unsigned long long bal = __ballot(valid);
  int nsel = __popc((unsigned)((bal >> gsh) & 0xFFFFull));

  // broadcast the group's 10 cols first (10 bpermutes, batched), then issue
  // 10 independent dwordx4 gathers back-to-back.
  int ck[KNB];
#pragma unroll
  for (int k = 0; k < KNB; ++k) ck[k] = __shfl(scol, gsh + k);

  const uint4* xh4 = reinterpret_cast<const uint4*>(xh);
  uint4 uu[KNB];
  float wj[KNB];
#pragma unroll
  for (int k = 0; k < KNB; ++k) {
    bool vk = (unsigned)ck[k] < (unsigned)N;
    wj[k] = vk ? 1.f : 0.f;
    uu[k] = xh4[(size_t)(vk ? ck[k] : 0) * 16 + j16];
  }

  if (!active) return;

  float acc[8];
#pragma unroll
  for (int q = 0; q < 8; ++q) acc[q] = 0.f;

  if (nsel > 0) {
#pragma unroll
    for (int k = 0; k < KNB; ++k) {
      float w = wj[k];
      acc[0] += w * bflo(uu[k].x); acc[1] += w * bfhi(uu[k].x);
      acc[2] += w * bflo(uu[k].y); acc[3] += w * bfhi(uu[k].y);
      acc[4] += w * bflo(uu[k].z); acc[5] += w * bfhi(uu[k].z);
      acc[6] += w * bflo(uu[k].w); acc[7] += w * bfhi(uu[k].w);
    }
    float sc = 1.f / (float)nsel;
#pragma unroll
    for (int q = 0; q < 8; ++q) acc[q] *= sc;
  } else {
    const float4* xr = reinterpret_cast<const float4*>(x + (size_t)n * D);
    float4 v0 = xr[j16 * 2], v1 = xr[j16 * 2 + 1];
    acc[0] = v0.x; acc[1] = v0.y; acc[2] = v0.z; acc[3] = v0.w;
    acc[4] = v1.x; acc[5] = v1.y; acc[6] = v1.z; acc[7] = v1.w;
  }

  uint4 o;
  o.x = bf16_rne(acc[0]) | (bf16_rne(acc[1]) << 16);
  o.y = bf16_rne(acc[2]) | (bf16_rne(acc[3]) << 16);
  o.z = bf16_rne(acc[4]) | (bf16_rne(acc[5]) << 16);
  o.w = bf16_rne(acc[6]) | (bf16_rne(acc[7]) << 16);
  reinterpret_cast<uint4*>(aggbh)[(size_t)n * 16 + j16] = o;
}

// ---------------------------------------------------------------------------
// fallback fp32-agg variants (R4-proven), updated for cols-in-slots
// ---------------------------------------------------------------------------
__global__ __launch_bounds__(256) void k_agg_h(const unsigned* __restrict__ xh,
                                               const float* __restrict__ x,
                                               const int* __restrict__ slots,
                                               float* __restrict__ agg, int N) {
  int wave = threadIdx.x >> 6;
  int lane = threadIdx.x & 63;
  int n = blockIdx.x * 4 + wave;
  if (n >= N) return;
  int c = -1;
  if (lane < KNB) c = slots[(size_t)n * KNB + lane];
  bool valid = (lane < KNB) && ((unsigned)c < (unsigned)N);
  unsigned long long m = __ballot(valid);
  int nsel = __popcll(m);
  float ax = 0.f, ay = 0.f;
  if (nsel > 0) {
    unsigned long long mm = m;
    while (mm) {
      int j = (int)__builtin_ctzll(mm);
      mm &= mm - 1;
      int cj = __shfl(c, j);
      if ((unsigned)cj >= (unsigned)N) cj = 0;
      unsigned u = xh[(size_t)cj * 64 + lane];
      ax += bflo(u);
      ay += bfhi(u);
    }
    float sc = 1.f / (float)nsel;
    ax *= sc; ay *= sc;
  } else {
    float2 v = reinterpret_cast<const float2*>(x + (size_t)n * D)[lane];
    ax = v.x; ay = v.y;
  }
  reinterpret_cast<float2*>(agg + (size_t)n * D)[lane] = make_float2(ax, ay);
}

__global__ __launch_bounds__(256) void k_agg(const float* __restrict__ x,
                                             const int* __restrict__ slots,
                                             float* __restrict__ agg,
                                             int N) {
  int wave = threadIdx.x >> 6;
  int lane = threadIdx.x & 63;
  int n = blockIdx.x * 4 + wave;
  if (n >= N) return;
  int c = -1;
  if (lane < KNB) c = slots[(size_t)n * KNB + lane];
  bool valid = (lane < KNB) && ((unsigned)c < (unsigned)N);
  unsigned long long m = __ballot(valid);
  int nsel = __popcll(m);
  float2 acc = make_float2(0.f, 0.f);
  if (nsel > 0) {
    unsigned long long mm = m;
    while (mm) {
      int j = (int)__builtin_ctzll(mm);
      mm &= mm - 1;
      int cj = __shfl(c, j);
      if ((unsigned)cj >= (unsigned)N) cj = 0;
      float2 v = reinterpret_cast<const float2*>(x + (size_t)cj * D)[lane];
      acc.x += v.x; acc.y += v.y;
    }
    float sc = 1.f / (float)nsel;
    acc.x *= sc; acc.y *= sc;
  } else {
    acc = reinterpret_cast<const float2*>(x + (size_t)n * D)[lane];
  }
  reinterpret_cast<float2*>(agg + (size_t)n * D)[lane] = acc;
}

// ---------------------------------------------------------------------------
// k_gemm_bf: out[n][o] = b[o] + sum_k aggbh[n][k]*W[o][k], bf16 MFMA 16x16x32.
// A read from ws (bf16), out only written -> no aliasing at all.
// Frag layouts (HW-verified m89): A/B lane holds 8 elems at k=quad*8+j;
// C/D col=lane&15, row=quad*4+reg.
// ---------------------------------------------------------------------------
#define GBN 128
#define LDK 136

__global__ __launch_bounds__(256) void k_gemm_bf(const unsigned short* __restrict__ aggbh,
                                                 const float* __restrict__ Wm,
                                                 const float* __restrict__ bias,
                                                 float* __restrict__ out, int N) {
  __shared__ unsigned short sA[GBN * LDK];
  __shared__ unsigned short sW[GBN * LDK];
  const int tid = threadIdx.x;
  const int n0 = blockIdx.x * GBN;

#pragma unroll
  for (int i = 0; i < 8; ++i) {
    int q = i * 256 + tid;
    int row = q >> 4;
    int c16 = q & 15;
    uint4 v = make_uint4(0u, 0u, 0u, 0u);
    if (n0 + row < N)
      v = reinterpret_cast<const uint4*>(aggbh + (size_t)(n0 + row) * D)[c16];
    *reinterpret_cast<uint4*>(&sA[row * LDK + c16 * 8]) = v;
  }
#pragma unroll
  for (int i = 0; i < 16; ++i) {
    int q = i * 256 + tid;
    int row = q >> 5;
    int c4 = q & 31;
    float4 wv = reinterpret_cast<const float4*>(Wm + (size_t)row * D)[c4];
    ushort4 uw;
    uw.x = (unsigned short)bf16_rne(wv.x);
    uw.y = (unsigned short)bf16_rne(wv.y);
    uw.z = (unsigned short)bf16_rne(wv.z);
    uw.w = (unsigned short)bf16_rne(wv.w);
    *reinterpret_cast<ushort4*>(&sW[row * LDK + c4 * 4]) = uw;
  }
  __syncthreads();

  const int wave = tid >> 6;
  const int lane = tid & 63;
  const int lrow = lane & 15;
  const int quad = lane >> 4;

  floatx4 acc[2][8];
#pragma unroll
  for (int mt = 0; mt < 2; ++mt)
#pragma unroll
    for (int nt = 0; nt < 8; ++nt)
      acc[mt][nt] = (floatx4){0.f, 0.f, 0.f, 0.f};

  float bv[8];
#pragma unroll
  for (int nt = 0; nt < 8; ++nt) bv[nt] = bias[nt * 16 + lrow];

#pragma unroll
  for (int ks = 0; ks < 4; ++ks) {
    int koff = ks * 32 + quad * 8;
    short8 a0 = *reinterpret_cast<const short8*>(&sA[(wave * 32 + lrow) * LDK + koff]);
    short8 a1 = *reinterpret_cast<const short8*>(&sA[(wave * 32 + 16 + lrow) * LDK + koff]);
#pragma unroll
    for (int nt = 0; nt < 8; ++nt) {
      short8 b = *reinterpret_cast<const short8*>(&sW[(nt * 16 + lrow) * LDK + koff]);
      acc[0][nt] = __builtin_amdgcn_mfma_f32_16x16x32_bf16(a0, b, acc[0][nt], 0, 0, 0);
      acc[1][nt] = __builtin_amdgcn_mfma_f32_16x16x32_bf16(a1, b, acc[1][nt], 0, 0, 0);
    }
  }

#pragma unroll
  for (int mt = 0; mt < 2; ++mt) {
    int rbase = n0 + wave * 32 + mt * 16 + quad * 4;
#pragma unroll
    for (int reg = 0; reg < 4; ++reg) {
      int r = rbase + reg;
      if (r < N) {
        float* op = out + (size_t)r * D + lrow;
#pragma unroll
        for (int nt = 0; nt < 8; ++nt)
          op[nt * 16] = acc[mt][nt][reg] + bv[nt];
      }
    }
  }
}

// ---------------------------------------------------------------------------
// fallback fp32 VALU GEMM (R2/R4-proven, in-place safe)
// ---------------------------------------------------------------------------
#define BN 128
#define KC 32
#define LDP 132

__global__ __launch_bounds__(256) void k_gemm(const float* __restrict__ agg,
                                              const float* __restrict__ Wm,
                                              const float* __restrict__ bias,
                                              float* __restrict__ out, int N) {
  __shared__ float sA[KC][LDP];
  __shared__ float sW[KC][LDP];
  const int tid = threadIdx.x;
  const int tx = tid & 15;
  const int ty = tid >> 4;
  const int n0 = blockIdx.x * BN;

  float acc[8][8];
#pragma unroll
  for (int i = 0; i < 8; ++i)
#pragma unroll
    for (int j = 0; j < 8; ++j) acc[i][j] = 0.f;

  const int nl = tid >> 3;
  const int kq = tid & 7;

  for (int kc = 0; kc < D; kc += KC) {
#pragma unroll
    for (int i = 0; i < 4; ++i) {
      int rrow = nl + i * 32;
      int n = n0 + rrow;
      float4 av = make_float4(0.f, 0.f, 0.f, 0.f);
      if (n < N)
        av = reinterpret_cast<const float4*>(agg + (size_t)n * D + kc)[kq];
      int k = kq * 4;
      sA[k+0][rrow] = av.x; sA[k+1][rrow] = av.y;
      sA[k+2][rrow] = av.z; sA[k+3][rrow] = av.w;
      float4 wv = reinterpret_cast<const float4*>(Wm + (size_t)rrow * D + kc)[kq];
      sW[k+0][rrow] = wv.x; sW[k+1][rrow] = wv.y;
      sW[k+2][rrow] = wv.z; sW[k+3][rrow] = wv.w;
    }
    __syncthreads();
#pragma unroll
    for (int k = 0; k < KC; ++k) {
      float4 a0 = *reinterpret_cast<const float4*>(&sA[k][ty * 8]);
      float4 a1 = *reinterpret_cast<const float4*>(&sA[k][ty * 8 + 4]);
      float4 w0 = *reinterpret_cast<const float4*>(&sW[k][tx * 8]);
      float4 w1 = *reinterpret_cast<const float4*>(&sW[k][tx * 8 + 4]);
      float a[8] = {a0.x, a0.y, a0.z, a0.w, a1.x, a1.y, a1.z, a1.w};
      float w[8] = {w0.x, w0.y, w0.z, w0.w, w1.x, w1.y, w1.z, w1.w};
#pragma unroll
      for (int i = 0; i < 8; ++i)
#pragma unroll
        for (int j = 0; j < 8; ++j)
          acc[i][j] += a[i] * w[j];
    }
    __syncthreads();
  }

  float4 b0 = reinterpret_cast<const float4*>(bias)[tx * 2];
  float4 b1 = reinterpret_cast<const float4*>(bias)[tx * 2 + 1];
#pragma unroll
  for (int i = 0; i < 8; ++i) {
    int n = n0 + ty * 8 + i;
    if (n < N) {
      float4 v0 = make_float4(acc[i][0] + b0.x, acc[i][1] + b0.y,
                              acc[i][2] + b0.z, acc[i][3] + b0.w);
      float4 v1 = make_float4(acc[i][4] + b1.x, acc[i][5] + b1.y,
                              acc[i][6] + b1.z, acc[i][7] + b1.w);
      float4* op = reinterpret_cast<float4*>(out + (size_t)n * D + tx * 8);
      op[0] = v0;
      op[1] = v1;
    }
  }
}

// ---------------------------------------------------------------------------
extern "C" void kernel_launch(void* const* d_in, const int* in_sizes, int n_in,
                              void* d_out, int out_size, void* d_ws, size_t ws_size,
                              hipStream_t stream) {
  const float* x    = (const float*)d_in[0];
  const int*   ei   = (const int*)d_in[1];
  const float* Wm   = (const float*)d_in[2];
  const float* bias = (const float*)d_in[3];
  float* out = (float*)d_out;

  const int N = in_sizes[0] / D;
  const int E = in_sizes[1] / 2;
  const int NB = (N + NPB - 1) >> SHIFT;

  // ws layout: counts|bases|cursor | slots[N*10] | xh (N*256B) | aggbh (N*256B)
  int* counts = (int*)d_ws;
  int* bases  = counts + NB;
  int* cursor = bases + NB;
  size_t off_slots = ((size_t)(3 * NB) * 4 + 15) & ~(size_t)15;
  int* slots = (int*)((char*)d_ws + off_slots);
  size_t off_xh = (off_slots + (size_t)N * KNB * 4 + 15) & ~(size_t)15;
  unsigned* xh = (unsigned*)((char*)d_ws + off_xh);
  size_t off_ab = off_xh + (size_t)N * D * 2;
  unsigned* aggbh = (unsigned*)((char*)d_ws + off_ab);

  const bool have_xh = ws_size >= off_xh + (size_t)N * D * 2;
  const bool have_ab = ws_size >= off_ab + (size_t)N * D * 2;

  unsigned* binned = (unsigned*)d_out;  // staged in d_out, dead after k_select
  const int blocks_bin = (E + EPB - 1) / EPB;
  const int n8 = N * (D / 8);
  const int xblocks = have_xh ? (n8 + T_BIN - 1) / T_BIN : 0;

  k_init<<<(NB + 255) / 256, 256, 0, stream>>>(counts, NB);
  k_count_xcast<<<blocks_bin + xblocks, T_BIN, 0, stream>>>(ei, E, NB, counts,
                                                            blocks_bin, x, xh, n8);
  k_scan<<<1, MAXNB, 0, stream>>>(counts, NB, bases, cursor);
  k_scatter2<<<blocks_bin, T_BIN, 0, stream>>>(ei, E, NB, cursor, binned);
  k_select<<<NB, 256, 0, stream>>>(binned, bases, counts, ei, slots, N, E);

  if (have_ab) {
    k_agg_hb<<<(N + 15) / 16, 256, 0, stream>>>(xh, x, slots, aggbh, N);
    k_gemm_bf<<<(N + GBN - 1) / GBN, 256, 0, stream>>>(
        (const unsigned short*)aggbh, Wm, bias, out, N);
  } else if (have_xh) {
    k_agg_h<<<(N + 3) / 4, 256, 0, stream>>>(xh, x, slots, out, N);
    k_gemm<<<(N + BN - 1) / BN, 256, 0, stream>>>(out, Wm, bias, out, N);
  } else {
    k_agg<<<(N + 3) / 4, 256, 0, stream>>>(x, slots, out, N);
    k_gemm<<<(N + BN - 1) / BN, 256, 0, stream>>>(out, Wm, bias, out, N);
  }
}

// Round 2
// 224.067 us; speedup vs baseline: 1.0684x; 1.0376x over previous
//
#include <hip/hip_runtime.h>
#include <hip/hip_bf16.h>
#include <cstdint>
#include <cstddef>

#define D 128           // feature dim
#define KNB 10          // NUM_NEIGHBORS
#define SENT 0x7FFFFFFF
#define SHIFT 8         // nodes per bucket = 256
#define NPB 256
#define T_BIN 256
#define EPB 4096        // edges per binning block
#define MAXNB 1024

typedef __attribute__((ext_vector_type(8))) short short8;   // MFMA A/B frag (8 bf16)
typedef __attribute__((ext_vector_type(4))) float floatx4;  // MFMA C/D frag

__device__ inline unsigned bf16_rne(float f) {
  unsigned u = __builtin_bit_cast(unsigned, f);
  return (u + 0x7FFFu + ((u >> 16) & 1u)) >> 16;
}
__device__ inline float bflo(unsigned u) { return __builtin_bit_cast(float, u << 16); }
__device__ inline float bfhi(unsigned u) { return __builtin_bit_cast(float, u & 0xFFFF0000u); }

// ---------------------------------------------------------------------------
// k_init: counts[0..NB)=0 only (slots init dropped in R7 — k_select writes
// every entry of slots[0, N*KNB)).
// ---------------------------------------------------------------------------
__global__ __launch_bounds__(256) void k_init(int* __restrict__ counts, int NB) {
  int i = blockIdx.x * 256 + threadIdx.x;
  if (i < NB) counts[i] = 0;
}

// ---------------------------------------------------------------------------
// k_count_xcast: blocks [0,blocks_bin) do the LDS-histogram edge count;
// blocks [blocks_bin,..) stream-cast x fp32 -> xh bf16 pairs (overlapped).
// ---------------------------------------------------------------------------
__global__ __launch_bounds__(T_BIN) void k_count_xcast(const int* __restrict__ row, int E,
                                                       int NB, int* __restrict__ counts,
                                                       int blocks_bin,
                                                       const float* __restrict__ x,
                                                       unsigned* __restrict__ xh, int n8) {
  if ((int)blockIdx.x < blocks_bin) {
    __shared__ int hist[MAXNB];
    for (int i = threadIdx.x; i < NB; i += T_BIN) hist[i] = 0;
    __syncthreads();
    int e0 = blockIdx.x * EPB;
    for (int i = threadIdx.x; i < EPB; i += T_BIN) {
      int e = e0 + i;
      if (e < E) atomicAdd(&hist[row[e] >> SHIFT], 1);
    }
    __syncthreads();
    for (int i = threadIdx.x; i < NB; i += T_BIN)
      if (hist[i]) atomicAdd(&counts[i], hist[i]);
  } else {
    int t = ((int)blockIdx.x - blocks_bin) * T_BIN + threadIdx.x;
    if (t >= n8) return;
    const float4* p = reinterpret_cast<const float4*>(x) + (size_t)t * 2;
    float4 a = p[0], b = p[1];
    uint4 o;
    o.x = bf16_rne(a.x) | (bf16_rne(a.y) << 16);
    o.y = bf16_rne(a.z) | (bf16_rne(a.w) << 16);
    o.z = bf16_rne(b.x) | (bf16_rne(b.y) << 16);
    o.w = bf16_rne(b.z) | (bf16_rne(b.w) << 16);
    reinterpret_cast<uint4*>(xh)[t] = o;
  }
}

// ---------------------------------------------------------------------------
__global__ __launch_bounds__(MAXNB) void k_scan(const int* __restrict__ counts, int NB,
                                                int* __restrict__ bases,
                                                int* __restrict__ cursor) {
  __shared__ int buf[MAXNB];
  int t = threadIdx.x;
  int v = (t < NB) ? counts[t] : 0;
  buf[t] = v;
  __syncthreads();
  for (int off = 1; off < MAXNB; off <<= 1) {
    int xv = (t >= off) ? buf[t - off] : 0;
    __syncthreads();
    buf[t] += xv;
    __syncthreads();
  }
  if (t < NB) {
    int base = buf[t] - v;
    bases[t] = base;
    cursor[t] = base;
  }
}

// ---------------------------------------------------------------------------
// bin edges into bucket regions; entry = (row&255)<<24 | edge_id (E < 2^24)
// ---------------------------------------------------------------------------
__global__ __launch_bounds__(T_BIN) void k_scatter2(const int* __restrict__ row, int E,
                                                    int NB, int* __restrict__ cursor,
                                                    unsigned* __restrict__ binned) {
  __shared__ int hist[MAXNB];
  __shared__ int lbase[MAXNB];
  for (int i = threadIdx.x; i < NB; i += T_BIN) hist[i] = 0;
  __syncthreads();
  int e0 = blockIdx.x * EPB;
  for (int i = threadIdx.x; i < EPB; i += T_BIN) {
    int e = e0 + i;
    if (e < E) atomicAdd(&hist[row[e] >> SHIFT], 1);
  }
  __syncthreads();
  for (int i = threadIdx.x; i < NB; i += T_BIN) {
    int h = hist[i];
    lbase[i] = h ? atomicAdd(&cursor[i], h) : 0;
  }
  __syncthreads();
  for (int i = threadIdx.x; i < NB; i += T_BIN) hist[i] = 0;  // reuse as cursor
  __syncthreads();
  for (int i = threadIdx.x; i < EPB; i += T_BIN) {
    int e = e0 + i;
    if (e < E) {
      int r = row[e];
      int b = r >> SHIFT;
      int pos = lbase[b] + atomicAdd(&hist[b], 1);
      binned[pos] = ((unsigned)(r & (NPB - 1)) << 24) | (unsigned)e;
    }
  }
}

// ---------------------------------------------------------------------------
// one WG per bucket: LDS atomicMin cascade -> 10 smallest edge ids per node.
// Dump maps edge-id -> COLUMN (ei[E+eid]) before writing slots (R7): the mean
// needs only the SET of first-10 edges, so storing cols is equivalent, and it
// removes the serial ei hop from the aggregation latency chain.
// HARDENING: (unsigned)v < E rejects SENT/poison BEFORE indexing ei.
// ---------------------------------------------------------------------------
__global__ __launch_bounds__(256) void k_select(const unsigned* __restrict__ binned,
                                                const int* __restrict__ bases,
                                                const int* __restrict__ counts,
                                                const int* __restrict__ ei,
                                                int* __restrict__ slots_g, int N, int E) {
  __shared__ int sl[NPB * KNB];
  int b = blockIdx.x;
  int nbase = b << SHIFT;
  int nloc = min(NPB, N - nbase);
  for (int i = threadIdx.x; i < nloc * KNB; i += 256) sl[i] = SENT;
  __syncthreads();
  int base = bases[b];
  int cnt = counts[b];
  if (cnt > E) cnt = E;  // hardening
  for (int i = threadIdx.x; i < cnt; i += 256) {
    unsigned en = binned[base + i];
    int rl = (int)(en >> 24);
    int v = (int)(en & 0xFFFFFFu);
    int* s = &sl[rl * KNB];
#pragma unroll
    for (int k = 0; k < KNB; ++k) {
      int old = atomicMin(&s[k], v);
      if (old == SENT) break;
      v = v > old ? v : old;
    }
  }
  __syncthreads();
  for (int i = threadIdx.x; i < nloc * KNB; i += 256) {
    int v = sl[i];
    int col = ((unsigned)v < (unsigned)E) ? ei[(size_t)E + v] : -1;
    slots_g[(size_t)nbase * KNB + i] = col;
  }
}

// ---------------------------------------------------------------------------
// k_fused: R8 — aggregation + GEMM in ONE kernel. Deletes the aggbh round
// trip (25.6 MB write + 25.6 MB read) and overlaps MFMA blocks with
// fabric-stalled gather blocks (R7 evidence: gather rate is L2-miss-path
// limited at ~3.5 TB/s, independent of occupancy/MLP — so idle VALU/MFMA
// capacity during gathers is free to spend on the GEMM of other blocks).
//
// Per 128-node block (256 thr, 69.6 KB LDS — same footprint as old gemm):
//  phase W: stage W fp32->bf16 into sW (issued first, long-latency).
//  phase G: 16 16-lane groups x 8 nodes each: 10 col-broadcasts + 10
//           independent uint4 bf16 gathers, fp32 mean, pack -> sA A-tile.
//           (identical arithmetic to the R7-verified k_agg_hb)
//  phase M: verified 16x16x32 bf16 MFMA body, bias add, fp32 out.
// HARDENING (load-bearing): col range-checked ((unsigned)c < N) before
// indexing xh; invalid/SENT/poison -> weight 0, gather row 0 (hot line).
// ---------------------------------------------------------------------------
#define GBN 128
#define LDK 136

__global__ __launch_bounds__(256) void k_fused(const unsigned* __restrict__ xh,
                                               const float* __restrict__ x,
                                               const int* __restrict__ slots,
                                               const float* __restrict__ Wm,
                                               const float* __restrict__ bias,
                                               float* __restrict__ out, int N) {
  __shared__ unsigned short sA[GBN * LDK];
  __shared__ unsigned short sW[GBN * LDK];
  const int tid = threadIdx.x;
  const int n0 = blockIdx.x * GBN;

  // ---- phase W: W fp32 -> bf16 into sW (same layout as old k_gemm_bf) ----
#pragma unroll
  for (int i = 0; i < 16; ++i) {
    int q = i * 256 + tid;
    int row = q >> 5;
    int c4 = q & 31;
    float4 wv = reinterpret_cast<const float4*>(Wm + (size_t)row * D)[c4];
    ushort4 uw;
    uw.x = (unsigned short)bf16_rne(wv.x);
    uw.y = (unsigned short)bf16_rne(wv.y);
    uw.z = (unsigned short)bf16_rne(wv.z);
    uw.w = (unsigned short)bf16_rne(wv.w);
    *reinterpret_cast<ushort4*>(&sW[row * LDK + c4 * 4]) = uw;
  }

  // ---- phase G: aggregate 8 nodes per 16-lane group, write A-tile ----
  const int lane = tid & 63;
  const int j16 = lane & 15;       // dim-octet index within the 256B row
  const int gsh = lane & 48;       // group base lane within wave
  const int grp = tid >> 4;        // 0..15

  const uint4* xh4 = reinterpret_cast<const uint4*>(xh);

  for (int nn = 0; nn < 8; ++nn) {
    const int row = nn * 16 + grp;         // 0..127
    const int n = n0 + row;
    const bool active = n < N;

    int scol = -1;
    if (active && j16 < KNB) scol = slots[(size_t)n * KNB + j16];
    bool valid = (unsigned)scol < (unsigned)N;
    unsigned long long bal = __ballot(valid);
    int nsel = __popc((unsigned)((bal >> gsh) & 0xFFFFull));

    // broadcast the group's 10 cols, then 10 independent 16B gathers
    int ck[KNB];
#pragma unroll
    for (int k = 0; k < KNB; ++k) ck[k] = __shfl(scol, gsh + k);

    uint4 uu[KNB];
    float wj[KNB];
#pragma unroll
    for (int k = 0; k < KNB; ++k) {
      bool vk = (unsigned)ck[k] < (unsigned)N;
      wj[k] = vk ? 1.f : 0.f;
      uu[k] = xh4[(size_t)(vk ? ck[k] : 0) * 16 + j16];
    }

    float acc[8];
#pragma unroll
    for (int q = 0; q < 8; ++q) acc[q] = 0.f;

    if (active) {
      if (nsel > 0) {
#pragma unroll
        for (int k = 0; k < KNB; ++k) {
          float w = wj[k];
          acc[0] += w * bflo(uu[k].x); acc[1] += w * bfhi(uu[k].x);
          acc[2] += w * bflo(uu[k].y); acc[3] += w * bfhi(uu[k].y);
          acc[4] += w * bflo(uu[k].z); acc[5] += w * bfhi(uu[k].z);
          acc[6] += w * bflo(uu[k].w); acc[7] += w * bfhi(uu[k].w);
        }
        float sc = 1.f / (float)nsel;
#pragma unroll
        for (int q = 0; q < 8; ++q) acc[q] *= sc;
      } else {
        const float4* xr = reinterpret_cast<const float4*>(x + (size_t)n * D);
        float4 v0 = xr[j16 * 2], v1 = xr[j16 * 2 + 1];
        acc[0] = v0.x; acc[1] = v0.y; acc[2] = v0.z; acc[3] = v0.w;
        acc[4] = v1.x; acc[5] = v1.y; acc[6] = v1.z; acc[7] = v1.w;
      }
    }

    ushort4 o;
    o.x = (unsigned short)(bf16_rne(acc[0]) | 0u); o.x = (unsigned short)bf16_rne(acc[0]);
    ushort4 ow;
    ow.x = (unsigned short)bf16_rne(acc[0]);
    ow.y = (unsigned short)bf16_rne(acc[1]);
    ow.z = (unsigned short)bf16_rne(acc[2]);
    ow.w = (unsigned short)bf16_rne(acc[3]);
    ushort4 ow2;
    ow2.x = (unsigned short)bf16_rne(acc[4]);
    ow2.y = (unsigned short)bf16_rne(acc[5]);
    ow2.z = (unsigned short)bf16_rne(acc[6]);
    ow2.w = (unsigned short)bf16_rne(acc[7]);
    *reinterpret_cast<ushort4*>(&sA[row * LDK + j16 * 8]) = ow;
    *reinterpret_cast<ushort4*>(&sA[row * LDK + j16 * 8 + 4]) = ow2;
  }
  __syncthreads();

  // ---- phase M: verified MFMA body (frag layouts HW-verified m89) ----
  const int wave = tid >> 6;
  const int lrow = lane & 15;
  const int quad = lane >> 4;

  floatx4 acc[2][8];
#pragma unroll
  for (int mt = 0; mt < 2; ++mt)
#pragma unroll
    for (int nt = 0; nt < 8; ++nt)
      acc[mt][nt] = (floatx4){0.f, 0.f, 0.f, 0.f};

  float bv[8];
#pragma unroll
  for (int nt = 0; nt < 8; ++nt) bv[nt] = bias[nt * 16 + lrow];

#pragma unroll
  for (int ks = 0; ks < 4; ++ks) {
    int koff = ks * 32 + quad * 8;
    short8 a0 = *reinterpret_cast<const short8*>(&sA[(wave * 32 + lrow) * LDK + koff]);
    short8 a1 = *reinterpret_cast<const short8*>(&sA[(wave * 32 + 16 + lrow) * LDK + koff]);
#pragma unroll
    for (int nt = 0; nt < 8; ++nt) {
      short8 b = *reinterpret_cast<const short8*>(&sW[(nt * 16 + lrow) * LDK + koff]);
      acc[0][nt] = __builtin_amdgcn_mfma_f32_16x16x32_bf16(a0, b, acc[0][nt], 0, 0, 0);
      acc[1][nt] = __builtin_amdgcn_mfma_f32_16x16x32_bf16(a1, b, acc[1][nt], 0, 0, 0);
    }
  }

#pragma unroll
  for (int mt = 0; mt < 2; ++mt) {
    int rbase = n0 + wave * 32 + mt * 16 + quad * 4;
#pragma unroll
    for (int reg = 0; reg < 4; ++reg) {
      int r = rbase + reg;
      if (r < N) {
        float* op = out + (size_t)r * D + lrow;
#pragma unroll
        for (int nt = 0; nt < 8; ++nt)
          op[nt * 16] = acc[mt][nt][reg] + bv[nt];
      }
    }
  }
}

// ---------------------------------------------------------------------------
// fallback fp32-agg variants (R4-proven), cols-in-slots
// ---------------------------------------------------------------------------
__global__ __launch_bounds__(256) void k_agg(const float* __restrict__ x,
                                             const int* __restrict__ slots,
                                             float* __restrict__ agg,
                                             int N) {
  int wave = threadIdx.x >> 6;
  int lane = threadIdx.x & 63;
  int n = blockIdx.x * 4 + wave;
  if (n >= N) return;
  int c = -1;
  if (lane < KNB) c = slots[(size_t)n * KNB + lane];
  bool valid = (lane < KNB) && ((unsigned)c < (unsigned)N);
  unsigned long long m = __ballot(valid);
  int nsel = __popcll(m);
  float2 acc = make_float2(0.f, 0.f);
  if (nsel > 0) {
    unsigned long long mm = m;
    while (mm) {
      int j = (int)__builtin_ctzll(mm);
      mm &= mm - 1;
      int cj = __shfl(c, j);
      if ((unsigned)cj >= (unsigned)N) cj = 0;
      float2 v = reinterpret_cast<const float2*>(x + (size_t)cj * D)[lane];
      acc.x += v.x; acc.y += v.y;
    }
    float sc = 1.f / (float)nsel;
    acc.x *= sc; acc.y *= sc;
  } else {
    acc = reinterpret_cast<const float2*>(x + (size_t)n * D)[lane];
  }
  reinterpret_cast<float2*>(agg + (size_t)n * D)[lane] = acc;
}

// ---------------------------------------------------------------------------
// fallback fp32 VALU GEMM (R2/R4-proven, in-place safe)
// ---------------------------------------------------------------------------
#define BN 128
#define KC 32
#define LDP 132

__global__ __launch_bounds__(256) void k_gemm(const float* __restrict__ agg,
                                              const float* __restrict__ Wm,
                                              const float* __restrict__ bias,
                                              float* __restrict__ out, int N) {
  __shared__ float sA[KC][LDP];
  __shared__ float sW[KC][LDP];
  const int tid = threadIdx.x;
  const int tx = tid & 15;
  const int ty = tid >> 4;
  const int n0 = blockIdx.x * BN;

  float acc[8][8];
#pragma unroll
  for (int i = 0; i < 8; ++i)
#pragma unroll
    for (int j = 0; j < 8; ++j) acc[i][j] = 0.f;

  const int nl = tid >> 3;
  const int kq = tid & 7;

  for (int kc = 0; kc < D; kc += KC) {
#pragma unroll
    for (int i = 0; i < 4; ++i) {
      int rrow = nl + i * 32;
      int n = n0 + rrow;
      float4 av = make_float4(0.f, 0.f, 0.f, 0.f);
      if (n < N)
        av = reinterpret_cast<const float4*>(agg + (size_t)n * D + kc)[kq];
      int k = kq * 4;
      sA[k+0][rrow] = av.x; sA[k+1][rrow] = av.y;
      sA[k+2][rrow] = av.z; sA[k+3][rrow] = av.w;
      float4 wv = reinterpret_cast<const float4*>(Wm + (size_t)rrow * D + kc)[kq];
      sW[k+0][rrow] = wv.x; sW[k+1][rrow] = wv.y;
      sW[k+2][rrow] = wv.z; sW[k+3][rrow] = wv.w;
    }
    __syncthreads();
#pragma unroll
    for (int k = 0; k < KC; ++k) {
      float4 a0 = *reinterpret_cast<const float4*>(&sA[k][ty * 8]);
      float4 a1 = *reinterpret_cast<const float4*>(&sA[k][ty * 8 + 4]);
      float4 w0 = *reinterpret_cast<const float4*>(&sW[k][tx * 8]);
      float4 w1 = *reinterpret_cast<const float4*>(&sW[k][tx * 8 + 4]);
      float a[8] = {a0.x, a0.y, a0.z, a0.w, a1.x, a1.y, a1.z, a1.w};
      float w[8] = {w0.x, w0.y, w0.z, w0.w, w1.x, w1.y, w1.z, w1.w};
#pragma unroll
      for (int i = 0; i < 8; ++i)
#pragma unroll
        for (int j = 0; j < 8; ++j)
          acc[i][j] += a[i] * w[j];
    }
    __syncthreads();
  }

  float4 b0 = reinterpret_cast<const float4*>(bias)[tx * 2];
  float4 b1 = reinterpret_cast<const float4*>(bias)[tx * 2 + 1];
#pragma unroll
  for (int i = 0; i < 8; ++i) {
    int n = n0 + ty * 8 + i;
    if (n < N) {
      float4 v0 = make_float4(acc[i][0] + b0.x, acc[i][1] + b0.y,
                              acc[i][2] + b0.z, acc[i][3] + b0.w);
      float4 v1 = make_float4(acc[i][4] + b1.x, acc[i][5] + b1.y,
                              acc[i][6] + b1.z, acc[i][7] + b1.w);
      float4* op = reinterpret_cast<float4*>(out + (size_t)n * D + tx * 8);
      op[0] = v0;
      op[1] = v1;
    }
  }
}

// ---------------------------------------------------------------------------
extern "C" void kernel_launch(void* const* d_in, const int* in_sizes, int n_in,
                              void* d_out, int out_size, void* d_ws, size_t ws_size,
                              hipStream_t stream) {
  const float* x    = (const float*)d_in[0];
  const int*   ei   = (const int*)d_in[1];
  const float* Wm   = (const float*)d_in[2];
  const float* bias = (const float*)d_in[3];
  float* out = (float*)d_out;

  const int N = in_sizes[0] / D;
  const int E = in_sizes[1] / 2;
  const int NB = (N + NPB - 1) >> SHIFT;

  // ws layout: counts|bases|cursor | slots[N*10] | xh (N*256B)
  int* counts = (int*)d_ws;
  int* bases  = counts + NB;
  int* cursor = bases + NB;
  size_t off_slots = ((size_t)(3 * NB) * 4 + 15) & ~(size_t)15;
  int* slots = (int*)((char*)d_ws + off_slots);
  size_t off_xh = (off_slots + (size_t)N * KNB * 4 + 15) & ~(size_t)15;
  unsigned* xh = (unsigned*)((char*)d_ws + off_xh);

  const bool have_xh = ws_size >= off_xh + (size_t)N * D * 2;

  unsigned* binned = (unsigned*)d_out;  // staged in d_out, dead after k_select
  const int blocks_bin = (E + EPB - 1) / EPB;
  const int n8 = N * (D / 8);
  const int xblocks = have_xh ? (n8 + T_BIN - 1) / T_BIN : 0;

  k_init<<<(NB + 255) / 256, 256, 0, stream>>>(counts, NB);
  k_count_xcast<<<blocks_bin + xblocks, T_BIN, 0, stream>>>(ei, E, NB, counts,
                                                            blocks_bin, x, xh, n8);
  k_scan<<<1, MAXNB, 0, stream>>>(counts, NB, bases, cursor);
  k_scatter2<<<blocks_bin, T_BIN, 0, stream>>>(ei, E, NB, cursor, binned);
  k_select<<<NB, 256, 0, stream>>>(binned, bases, counts, ei, slots, N, E);

  if (have_xh) {
    k_fused<<<(N + GBN - 1) / GBN, 256, 0, stream>>>(xh, x, slots, Wm, bias, out, N);
  } else {
    k_agg<<<(N + 3) / 4, 256, 0, stream>>>(x, slots, out, N);
    k_gemm<<<(N + BN - 1) / BN, 256, 0, stream>>>(out, Wm, bias, out, N);
  }
}